// Round 16
// baseline (417.607 us; speedup 1.0000x reference)
//
#include <hip/hip_runtime.h>

#define B_TOT 2048
#define M_SEQ 64
#define SDIM 32
#define CDIM 8
#define LDIM 128
#define HDIM 512

#define NROWS_NEXT (B_TOT * M_SEQ)       // 131072
#define NROWS_ALL  (NROWS_NEXT + B_TOT)  // 133120

typedef short bf16x8 __attribute__((ext_vector_type(8)));
typedef float f32x4  __attribute__((ext_vector_type(4)));
typedef float f32x4v __attribute__((ext_vector_type(4)));

__device__ __forceinline__ unsigned short f2bf(float f) {
    unsigned int u = __builtin_bit_cast(unsigned int, f);
    u = u + 0x7FFFu + ((u >> 16) & 1u);   // round-to-nearest-even
    return (unsigned short)(u >> 16);
}

// bf16 h-buffer swizzle (1024B rows): XOR bits 4-7 with row&15 (4-bit).
__device__ __forceinline__ unsigned int swz(unsigned int byte) {
    return byte ^ (((byte >> 10) & 15u) << 4);
}
// fp32 staging tile swizzle (512B rows), 4-bit
__device__ __forceinline__ unsigned int swzf(unsigned int byte) {
    return byte ^ (((byte >> 9) & 15u) << 4);
}

// ---------------------------------------------------------------------------
// Pack fp32 weight W[K][N] into bf16 fragment-major for 16x16x32 MFMA.
// ---------------------------------------------------------------------------
__device__ __forceinline__ void pack_one16(const float* __restrict__ W, short* __restrict__ out,
                                           int e, int N) {
    int j    = e & 7;
    int lane = (e >> 3) & 63;
    int tile = e >> 9;
    int NT   = N >> 4;
    int nt   = tile % NT;
    int kt   = tile / NT;
    int k = kt * 32 + ((lane >> 4) << 3) + j;
    int n = (nt << 4) + (lane & 15);
    out[e] = (short)f2bf(W[(size_t)k * N + n]);
}

#define P_S0 16384
#define P_S1 (P_S0 + 262144)
#define P_S2 (P_S1 + 262144)
#define P_S3 (P_S2 + 65536)   // 606208 total

__global__ void pack_all(const float* __restrict__ w0, const float* __restrict__ w1,
                         const float* __restrict__ w2, const float* __restrict__ w3,
                         short* __restrict__ o0, short* __restrict__ o1,
                         short* __restrict__ o2, short* __restrict__ o3) {
    int id = blockIdx.x * 256 + threadIdx.x;
    if (id < P_S0)      pack_one16(w0, o0, id, HDIM);
    else if (id < P_S1) pack_one16(w1, o1, id - P_S0, HDIM);
    else if (id < P_S2) pack_one16(w2, o2, id - P_S1, HDIM);
    else if (id < P_S3) pack_one16(w3, o3, id - P_S2, LDIM);
}

// ---------------------------------------------------------------------------
// O = X @ Y for 128x128 fp32 (A2 = A @ A). 128 blocks x 128 threads.
// ---------------------------------------------------------------------------
__global__ __launch_bounds__(128) void mm128(const float* __restrict__ X,
                                             const float* __restrict__ Y,
                                             float* __restrict__ O) {
    int r = blockIdx.x, c = threadIdx.x;
    float s = 0.f;
    for (int k = 0; k < 128; ++k) s += X[r * 128 + k] * Y[k * 128 + c];
    O[r * 128 + c] = s;
}

// ---------------------------------------------------------------------------
// MLP layer, 64-row tile, 16 waves. Wave w owns ntiles {2w,2w+1} x 4 mtiles
// (acc 32 regs). ZERO-COST B ROTATION: b0 is reloaded for kt+1 immediately
// after its last use (the 4 nt0-MFMAs), then the nt1-MFMAs run, then b1
// reloads. Steady-state B live-regs unchanged (16) -> occupancy should stay
// 8 waves/SIMD while each B-load issues ~half a kt-round before use.
// ---------------------------------------------------------------------------
__device__ __forceinline__ void layer16w(char* hbuf, const short* __restrict__ pw,
                                         const float* __restrict__ bias,
                                         int ktCount, int wave, int lane) {
    const int l15 = lane & 15;
    const int lhi = lane >> 4;
    const unsigned base0 = (unsigned)(l15 * 1024 + (lhi << 4));
    const unsigned xmask = ((unsigned)l15) << 4;

    f32x4 acc[4][2];
    #pragma unroll
    for (int mt = 0; mt < 4; ++mt)
        #pragma unroll
        for (int nt = 0; nt < 2; ++nt)
            acc[mt][nt] = (f32x4){0.f, 0.f, 0.f, 0.f};

    const short* p = pw + (wave * 2) * 512 + (lane << 3);   // kt stride = 16384
    bf16x8 b0 = *(const bf16x8*)(p);
    bf16x8 b1 = *(const bf16x8*)(p + 512);
    for (int kt = 0; kt < ktCount; ++kt) {
        const char* ab = hbuf + ((base0 + (unsigned)kt * 64u) ^ xmask);
        bf16x8 a0 = *(const bf16x8*)(ab);
        bf16x8 a1 = *(const bf16x8*)(ab + 16384);
        bf16x8 a2 = *(const bf16x8*)(ab + 32768);
        bf16x8 a3 = *(const bf16x8*)(ab + 49152);
        acc[0][0] = __builtin_amdgcn_mfma_f32_16x16x32_bf16(a0, b0, acc[0][0], 0, 0, 0);
        acc[1][0] = __builtin_amdgcn_mfma_f32_16x16x32_bf16(a1, b0, acc[1][0], 0, 0, 0);
        acc[2][0] = __builtin_amdgcn_mfma_f32_16x16x32_bf16(a2, b0, acc[2][0], 0, 0, 0);
        acc[3][0] = __builtin_amdgcn_mfma_f32_16x16x32_bf16(a3, b0, acc[3][0], 0, 0, 0);
        p += 16384;
        if (kt + 1 < ktCount) b0 = *(const bf16x8*)(p);         // rotate: b0 dead above
        acc[0][1] = __builtin_amdgcn_mfma_f32_16x16x32_bf16(a0, b1, acc[0][1], 0, 0, 0);
        acc[1][1] = __builtin_amdgcn_mfma_f32_16x16x32_bf16(a1, b1, acc[1][1], 0, 0, 0);
        acc[2][1] = __builtin_amdgcn_mfma_f32_16x16x32_bf16(a2, b1, acc[2][1], 0, 0, 0);
        acc[3][1] = __builtin_amdgcn_mfma_f32_16x16x32_bf16(a3, b1, acc[3][1], 0, 0, 0);
        if (kt + 1 < ktCount) b1 = *(const bf16x8*)(p + 512);   // rotate: b1 dead above
    }
    __syncthreads();   // all reads of hbuf done before in-place overwrite

    #pragma unroll
    for (int nt = 0; nt < 2; ++nt) {
        int colg = (wave * 2 + nt) * 16 + l15;
        float bv = bias[colg];
        #pragma unroll
        for (int mt = 0; mt < 4; ++mt) {
            #pragma unroll
            for (int r = 0; r < 4; ++r) {
                int row = mt * 16 + (lhi << 2) + r;
                float v = fmaxf(acc[mt][nt][r] + bv, 0.f);
                *(unsigned short*)(hbuf + swz((unsigned)(row * 1024 + colg * 2))) = f2bf(v);
            }
        }
    }
    __syncthreads();
}

// ---------------------------------------------------------------------------
// Fused encoder: 64 rows/block, 1024 threads (16 waves), 64KB LDS,
// 2 blocks/CU -> 32 waves/CU (8/SIMD).
// ---------------------------------------------------------------------------
__global__ __launch_bounds__(1024, 8) void encoder_kernel(
    const float* __restrict__ x_next, const float* __restrict__ x_k,
    const short* __restrict__ pw0, const short* __restrict__ pw1,
    const short* __restrict__ pw2, const short* __restrict__ pw3,
    const float* __restrict__ b0, const float* __restrict__ b1,
    const float* __restrict__ b2, const float* __restrict__ b3,
    float* __restrict__ z_target, float* __restrict__ z_k_out) {
    __shared__ __attribute__((aligned(16))) char hbuf[64 * 1024];
    const int tid  = threadIdx.x;
    const int wave = tid >> 6;
    const int lane = tid & 63;
    const int l15  = lane & 15;
    const int lhi  = lane >> 4;
    const int r0   = blockIdx.x * 64;

    const float* xin;
    float* zout;
    bool is_tgt = (r0 < NROWS_NEXT);
    if (is_tgt) {
        xin  = x_next + (size_t)r0 * SDIM;
        zout = z_target + (size_t)r0 * LDIM;
    } else {
        xin  = x_k + (size_t)(r0 - NROWS_NEXT) * SDIM;
        zout = z_k_out + (size_t)(r0 - NROWS_NEXT) * LDIM;
    }

    // stage 64x32 fp32 -> bf16 into h cols [0,32): threads 0..511
    if (tid < 512) {
        int row = tid >> 3;
        int c   = (tid & 7) * 4;
        float4 v = *(const float4*)(xin + row * SDIM + c);
        uint2 pk;
        pk.x = (unsigned int)f2bf(v.x) | ((unsigned int)f2bf(v.y) << 16);
        pk.y = (unsigned int)f2bf(v.z) | ((unsigned int)f2bf(v.w) << 16);
        *(uint2*)(hbuf + swz((unsigned)(row * 1024 + c * 2))) = pk;
    }
    __syncthreads();

    layer16w(hbuf, pw0, b0, 1, wave, lane);    // 32  -> 512, relu
    layer16w(hbuf, pw1, b1, 16, wave, lane);   // 512 -> 512, relu
    layer16w(hbuf, pw2, b2, 16, wave, lane);   // 512 -> 512, relu

    // layer 3: 512 -> 128. 32 cells = 16 waves x (1 ntile x 2 mtiles).
    // Wave w: ntile w&7, mtiles {(w>>3)*2, (w>>3)*2+1}. pw3 kt-stride 4096.
    // Same zero-cost B rotation.
    {
        const int nt8 = wave & 7;
        const int mb  = (wave >> 3) * 2;
        const unsigned base0 = (unsigned)(mb * 16384 + l15 * 1024 + (lhi << 4));
        const unsigned xmask = ((unsigned)l15) << 4;
        f32x4 acc[2];
        acc[0] = (f32x4){0.f, 0.f, 0.f, 0.f};
        acc[1] = (f32x4){0.f, 0.f, 0.f, 0.f};

        const short* p = pw3 + (nt8 << 9) + (lane << 3);
        bf16x8 b = *(const bf16x8*)(p);
        for (int kt = 0; kt < 16; ++kt) {
            const char* ab = hbuf + ((base0 + (unsigned)kt * 64u) ^ xmask);
            bf16x8 a0 = *(const bf16x8*)(ab);
            bf16x8 a1 = *(const bf16x8*)(ab + 16384);
            acc[0] = __builtin_amdgcn_mfma_f32_16x16x32_bf16(a0, b, acc[0], 0, 0, 0);
            acc[1] = __builtin_amdgcn_mfma_f32_16x16x32_bf16(a1, b, acc[1], 0, 0, 0);
            p += 4096;
            if (kt < 15) b = *(const bf16x8*)(p);   // rotate
        }
        __syncthreads();   // done reading bf16 h; reuse hbuf as [64][128] fp32

        int colg = nt8 * 16 + l15;
        float bv = b3[colg];
        #pragma unroll
        for (int mt = 0; mt < 2; ++mt) {
            #pragma unroll
            for (int r = 0; r < 4; ++r) {
                int row = (mb + mt) * 16 + (lhi << 2) + r;
                *(float*)(hbuf + swzf((unsigned)(row * 512 + colg * 4))) = acc[mt][r] + bv;
            }
        }
        __syncthreads();

        #pragma unroll
        for (int pass = 0; pass < 2; ++pass) {
            unsigned int L = (unsigned)(pass * 1024 + tid) * 16;
            f32x4v v = *(const f32x4v*)(hbuf + swzf(L));
            if (is_tgt) __builtin_nontemporal_store(v, (f32x4v*)(zout + (L >> 2)));
            else        *(f32x4v*)(zout + (L >> 2)) = v;
        }
    }
}

// ---------------------------------------------------------------------------
// 2-step unrolled recurrence + fused decoder — R13-VERBATIM.
// ---------------------------------------------------------------------------
#define RR4 4
__global__ __launch_bounds__(512, 4) void recurrence2_kernel(
    const float* __restrict__ zk, const float* __restrict__ u,
    const float* __restrict__ Bw, const float* __restrict__ Aw,
    const float* __restrict__ A2, const float* __restrict__ Cw,
    const float* __restrict__ Cb,
    float* __restrict__ zpred, float* __restrict__ xpred) {
    __shared__ float z_lds[RR4][128];
    __shared__ float part[4][8][128];
    __shared__ float zoutb[2][RR4][128];
    __shared__ float u_lds[RR4 * M_SEQ * CDIM];
    __shared__ float Bw_lds[CDIM * 128];
    __shared__ float Ct_lds[32 * 132];
    __shared__ float cb_lds[SDIM];
    const int tid   = threadIdx.x;
    const int col   = tid & 127;
    const int slice = tid >> 7;
    const int b0    = blockIdx.x * RR4;

    float a1[32], a2r[32], ba[16];
    #pragma unroll
    for (int i = 0; i < 32; ++i) {
        a1[i]  = Aw[(size_t)(slice * 32 + i) * 128 + col];
        a2r[i] = A2[(size_t)(slice * 32 + i) * 128 + col];
    }

    if (tid < RR4 * 128)
        z_lds[tid >> 7][tid & 127] = zk[(size_t)(b0 + (tid >> 7)) * 128 + (tid & 127)];
    for (int id = tid; id < CDIM * 128; id += 512) Bw_lds[id] = Bw[id];
    for (int id = tid; id < RR4 * M_SEQ * CDIM; id += 512)
        u_lds[id] = u[(size_t)b0 * M_SEQ * CDIM + id];
    for (int id = tid; id < 128 * 32; id += 512) {
        int k = id >> 5, c = id & 31;
        Ct_lds[c * 132 + k] = Cw[id];
    }
    if (tid < SDIM) cb_lds[tid] = Cb[tid];
    __syncthreads();

    #pragma unroll
    for (int c = 0; c < 8; ++c) {
        float s = 0.f;
        #pragma unroll
        for (int kk = 0; kk < 32; ++kk) s += Bw_lds[c * 128 + slice * 32 + kk] * a1[kk];
        part[slice][c][col] = s;
    }
    __syncthreads();
    #pragma unroll
    for (int c = 0; c < 8; ++c) {
        ba[c]     = Bw_lds[c * 128 + col];
        ba[8 + c] = part[0][c][col] + part[1][c][col] + part[2][c][col] + part[3][c][col];
    }
    __syncthreads();

    for (int r = 0; r < 32; ++r) {
        const int m0 = 2 * r;
        #pragma unroll
        for (int b = 0; b < RR4; ++b) {
            const float4* z4 = (const float4*)&z_lds[b][slice * 32];
            float p1 = 0.f, p2 = 0.f;
            #pragma unroll
            for (int i = 0; i < 8; ++i) {
                float4 zv = z4[i];
                p1 += a1[i*4+0]*zv.x + a1[i*4+1]*zv.y + a1[i*4+2]*zv.z + a1[i*4+3]*zv.w;
                p2 += a2r[i*4+0]*zv.x + a2r[i*4+1]*zv.y + a2r[i*4+2]*zv.z + a2r[i*4+3]*zv.w;
            }
            part[slice][b * 2 + 0][col] = p1;
            part[slice][b * 2 + 1][col] = p2;
        }
        if (r > 0 && tid < 256) {
            const int mprev = 2 * (r - 1);
            int sb = tid >> 5, c32 = tid & 31;
            int s = sb >> 2, b = sb & 3;
            float acc = cb_lds[c32];
            const float4* z4 = (const float4*)&zoutb[s][b][0];
            const float4* c4 = (const float4*)&Ct_lds[c32 * 132];
            #pragma unroll
            for (int i = 0; i < 32; ++i) {
                float4 zv = z4[i], cv = c4[i];
                acc += zv.x*cv.x + zv.y*cv.y + zv.z*cv.z + zv.w*cv.w;
            }
            __builtin_nontemporal_store(acc,
                xpred + ((size_t)(b0 + b) * M_SEQ + (mprev + s)) * SDIM + c32);
        }
        __syncthreads();
        {
            const int b = slice;
            float v0 = part[0][b*2+0][col] + part[1][b*2+0][col] + part[2][b*2+0][col] + part[3][b*2+0][col];
            float v1 = part[0][b*2+1][col] + part[1][b*2+1][col] + part[2][b*2+1][col] + part[3][b*2+1][col];
            const float4* uu0 = (const float4*)&u_lds[(b * M_SEQ + m0) * CDIM];
            float4 ua = uu0[0], ub = uu0[1];
            v0 += ua.x*ba[0] + ua.y*ba[1] + ua.z*ba[2] + ua.w*ba[3]
                + ub.x*ba[4] + ub.y*ba[5] + ub.z*ba[6] + ub.w*ba[7];
            v1 += ua.x*ba[8] + ua.y*ba[9] + ua.z*ba[10] + ua.w*ba[11]
                + ub.x*ba[12] + ub.y*ba[13] + ub.z*ba[14] + ub.w*ba[15];
            const float4* uu1 = (const float4*)&u_lds[(b * M_SEQ + m0 + 1) * CDIM];
            float4 uc = uu1[0], ud = uu1[1];
            v1 += uc.x*ba[0] + uc.y*ba[1] + uc.z*ba[2] + uc.w*ba[3]
                + ud.x*ba[4] + ud.y*ba[5] + ud.z*ba[6] + ud.w*ba[7];
            zoutb[0][b][col] = v0;
            zoutb[1][b][col] = v1;
            z_lds[b][col] = v1;
            __builtin_nontemporal_store(v0, zpred + ((size_t)(b0 + b) * M_SEQ + m0) * 128 + col);
            __builtin_nontemporal_store(v1, zpred + ((size_t)(b0 + b) * M_SEQ + m0 + 1) * 128 + col);
        }
        __syncthreads();
    }
    if (tid < 256) {
        const int mprev = 62;
        int sb = tid >> 5, c32 = tid & 31;
        int s = sb >> 2, b = sb & 3;
        float acc = cb_lds[c32];
        const float4* z4 = (const float4*)&zoutb[s][b][0];
        const float4* c4 = (const float4*)&Ct_lds[c32 * 132];
        #pragma unroll
        for (int i = 0; i < 32; ++i) {
            float4 zv = z4[i], cv = c4[i];
            acc += zv.x*cv.x + zv.y*cv.y + zv.z*cv.z + zv.w*cv.w;
        }
        __builtin_nontemporal_store(acc,
            xpred + ((size_t)(b0 + b) * M_SEQ + (mprev + s)) * SDIM + c32);
    }
}

extern "C" void kernel_launch(void* const* d_in, const int* in_sizes, int n_in,
                              void* d_out, int out_size, void* d_ws, size_t ws_size,
                              hipStream_t stream) {
    const float* x_k    = (const float*)d_in[0];
    const float* u_seq  = (const float*)d_in[1];
    const float* x_next = (const float*)d_in[2];
    const float* w0 = (const float*)d_in[3];  const float* b0 = (const float*)d_in[4];
    const float* w1 = (const float*)d_in[5];  const float* b1 = (const float*)d_in[6];
    const float* w2 = (const float*)d_in[7];  const float* b2 = (const float*)d_in[8];
    const float* w3 = (const float*)d_in[9];  const float* b3 = (const float*)d_in[10];
    const float* A_w = (const float*)d_in[11];
    const float* B_w = (const float*)d_in[12];
    const float* C_w = (const float*)d_in[13];
    const float* C_b = (const float*)d_in[14];

    float* out    = (float*)d_out;
    float* z_pred = out;                                   // 2048*64*128
    float* x_pred = out + (size_t)NROWS_NEXT * LDIM;       // 2048*64*32
    float* z_tgt  = x_pred + (size_t)NROWS_NEXT * SDIM;    // 2048*64*128

    char* ws = (char*)d_ws;
    short* pw0 = (short*)(ws);                                     // 32 KB
    short* pw1 = (short*)(ws + 32768);                             // 512 KB
    short* pw2 = (short*)(ws + 32768 + 524288);                    // 512 KB
    short* pw3 = (short*)(ws + 32768 + 2 * 524288);                // 128 KB
    float* z_k_buf = (float*)(ws + 32768 + 2 * 524288 + 131072);   // 1 MB
    float* A2_buf  = (float*)(ws + 32768 + 2 * 524288 + 131072 + 1048576);  // 64 KB

    mm128<<<128, 128, 0, stream>>>(A_w, A_w, A2_buf);

    pack_all<<<(P_S3 + 255) / 256, 256, 0, stream>>>(w0, w1, w2, w3, pw0, pw1, pw2, pw3);

    encoder_kernel<<<NROWS_ALL / 64, 1024, 0, stream>>>(
        x_next, x_k, pw0, pw1, pw2, pw3, b0, b1, b2, b3, z_tgt, z_k_buf);

    recurrence2_kernel<<<B_TOT / RR4, 512, 0, stream>>>(
        z_k_buf, u_seq, B_w, A_w, A2_buf, C_w, C_b, z_pred, x_pred);
}

// Round 17
// 388.705 us; speedup vs baseline: 1.0744x; 1.0744x over previous
//
#include <hip/hip_runtime.h>

#define B_TOT 2048
#define M_SEQ 64
#define SDIM 32
#define CDIM 8
#define LDIM 128
#define HDIM 512

#define NROWS_NEXT (B_TOT * M_SEQ)       // 131072
#define NROWS_ALL  (NROWS_NEXT + B_TOT)  // 133120

typedef short bf16x8 __attribute__((ext_vector_type(8)));
typedef float f32x4  __attribute__((ext_vector_type(4)));
typedef float f32x4v __attribute__((ext_vector_type(4)));

__device__ __forceinline__ unsigned short f2bf(float f) {
    unsigned int u = __builtin_bit_cast(unsigned int, f);
    u = u + 0x7FFFu + ((u >> 16) & 1u);   // round-to-nearest-even
    return (unsigned short)(u >> 16);
}

// bf16 h-buffer swizzle (1024B rows): XOR bits 4-7 with row&15 (4-bit).
__device__ __forceinline__ unsigned int swz(unsigned int byte) {
    return byte ^ (((byte >> 10) & 15u) << 4);
}
// fp32 staging tile swizzle (512B rows), 4-bit
__device__ __forceinline__ unsigned int swzf(unsigned int byte) {
    return byte ^ (((byte >> 9) & 15u) << 4);
}

// ---------------------------------------------------------------------------
// Pack fp32 weight W[K][N] into bf16 fragment-major for 16x16x32 MFMA.
// ---------------------------------------------------------------------------
__device__ __forceinline__ void pack_one16(const float* __restrict__ W, short* __restrict__ out,
                                           int e, int N) {
    int j    = e & 7;
    int lane = (e >> 3) & 63;
    int tile = e >> 9;
    int NT   = N >> 4;
    int nt   = tile % NT;
    int kt   = tile / NT;
    int k = kt * 32 + ((lane >> 4) << 3) + j;
    int n = (nt << 4) + (lane & 15);
    out[e] = (short)f2bf(W[(size_t)k * N + n]);
}

#define P_S0 16384
#define P_S1 (P_S0 + 262144)
#define P_S2 (P_S1 + 262144)
#define P_S3 (P_S2 + 65536)   // 606208 total

__global__ void pack_all(const float* __restrict__ w0, const float* __restrict__ w1,
                         const float* __restrict__ w2, const float* __restrict__ w3,
                         short* __restrict__ o0, short* __restrict__ o1,
                         short* __restrict__ o2, short* __restrict__ o3) {
    int id = blockIdx.x * 256 + threadIdx.x;
    if (id < P_S0)      pack_one16(w0, o0, id, HDIM);
    else if (id < P_S1) pack_one16(w1, o1, id - P_S0, HDIM);
    else if (id < P_S2) pack_one16(w2, o2, id - P_S1, HDIM);
    else if (id < P_S3) pack_one16(w3, o3, id - P_S2, LDIM);
}

// ---------------------------------------------------------------------------
// O = X @ Y for 128x128 fp32 (A2 = A @ A). 128 blocks x 128 threads.
// ---------------------------------------------------------------------------
__global__ __launch_bounds__(128) void mm128(const float* __restrict__ X,
                                             const float* __restrict__ Y,
                                             float* __restrict__ O) {
    int r = blockIdx.x, c = threadIdx.x;
    float s = 0.f;
    for (int k = 0; k < 128; ++k) s += X[r * 128 + k] * Y[k * 128 + c];
    O[r * 128 + c] = s;
}

// ---------------------------------------------------------------------------
// MLP layer — R15-EXACT (best measured: encoder 284us @ 80% occupancy).
// 64-row tile, 16 waves. Wave w owns ntiles {2w,2w+1} x all 4 mtiles:
// acc = 32 AGPR + 32 VGPR = exactly the 8-wave/SIMD envelope. No B-prefetch
// (R16 proved any lifetime extension spills ~110MB to scratch); TLP at the
// HW max (8 waves/SIMD) is the latency-hiding mechanism.
// ---------------------------------------------------------------------------
__device__ __forceinline__ void layer16w(char* hbuf, const short* __restrict__ pw,
                                         const float* __restrict__ bias,
                                         int ktCount, int wave, int lane) {
    const int l15 = lane & 15;
    const int lhi = lane >> 4;
    const unsigned base0 = (unsigned)(l15 * 1024 + (lhi << 4));
    const unsigned xmask = ((unsigned)l15) << 4;

    f32x4 acc[4][2];
    #pragma unroll
    for (int mt = 0; mt < 4; ++mt)
        #pragma unroll
        for (int nt = 0; nt < 2; ++nt)
            acc[mt][nt] = (f32x4){0.f, 0.f, 0.f, 0.f};

    const short* p = pw + (wave * 2) * 512 + (lane << 3);   // kt stride = 16384
    for (int kt = 0; kt < ktCount; ++kt) {
        bf16x8 b0 = *(const bf16x8*)(p);
        bf16x8 b1 = *(const bf16x8*)(p + 512);
        const char* ab = hbuf + ((base0 + (unsigned)kt * 64u) ^ xmask);
        #pragma unroll
        for (int mt = 0; mt < 4; ++mt) {
            bf16x8 a = *(const bf16x8*)(ab + mt * 16384);
            acc[mt][0] = __builtin_amdgcn_mfma_f32_16x16x32_bf16(a, b0, acc[mt][0], 0, 0, 0);
            acc[mt][1] = __builtin_amdgcn_mfma_f32_16x16x32_bf16(a, b1, acc[mt][1], 0, 0, 0);
        }
        p += 16384;
    }
    __syncthreads();   // all reads of hbuf done before in-place overwrite

    #pragma unroll
    for (int nt = 0; nt < 2; ++nt) {
        int colg = (wave * 2 + nt) * 16 + l15;
        float bv = bias[colg];
        #pragma unroll
        for (int mt = 0; mt < 4; ++mt) {
            #pragma unroll
            for (int r = 0; r < 4; ++r) {
                int row = mt * 16 + (lhi << 2) + r;
                float v = fmaxf(acc[mt][nt][r] + bv, 0.f);
                *(unsigned short*)(hbuf + swz((unsigned)(row * 1024 + colg * 2))) = f2bf(v);
            }
        }
    }
    __syncthreads();
}

// ---------------------------------------------------------------------------
// Fused encoder: 64 rows/block, 1024 threads (16 waves), 64KB LDS,
// 2 blocks/CU -> 32 waves/CU (8/SIMD, HW max).
// ---------------------------------------------------------------------------
__global__ __launch_bounds__(1024, 8) void encoder_kernel(
    const float* __restrict__ x_next, const float* __restrict__ x_k,
    const short* __restrict__ pw0, const short* __restrict__ pw1,
    const short* __restrict__ pw2, const short* __restrict__ pw3,
    const float* __restrict__ b0, const float* __restrict__ b1,
    const float* __restrict__ b2, const float* __restrict__ b3,
    float* __restrict__ z_target, float* __restrict__ z_k_out) {
    __shared__ __attribute__((aligned(16))) char hbuf[64 * 1024];
    const int tid  = threadIdx.x;
    const int wave = tid >> 6;
    const int lane = tid & 63;
    const int l15  = lane & 15;
    const int lhi  = lane >> 4;
    const int r0   = blockIdx.x * 64;

    const float* xin;
    float* zout;
    bool is_tgt = (r0 < NROWS_NEXT);
    if (is_tgt) {
        xin  = x_next + (size_t)r0 * SDIM;
        zout = z_target + (size_t)r0 * LDIM;
    } else {
        xin  = x_k + (size_t)(r0 - NROWS_NEXT) * SDIM;
        zout = z_k_out + (size_t)(r0 - NROWS_NEXT) * LDIM;
    }

    // stage 64x32 fp32 -> bf16 into h cols [0,32): threads 0..511
    if (tid < 512) {
        int row = tid >> 3;
        int c   = (tid & 7) * 4;
        float4 v = *(const float4*)(xin + row * SDIM + c);
        uint2 pk;
        pk.x = (unsigned int)f2bf(v.x) | ((unsigned int)f2bf(v.y) << 16);
        pk.y = (unsigned int)f2bf(v.z) | ((unsigned int)f2bf(v.w) << 16);
        *(uint2*)(hbuf + swz((unsigned)(row * 1024 + c * 2))) = pk;
    }
    __syncthreads();

    layer16w(hbuf, pw0, b0, 1, wave, lane);    // 32  -> 512, relu
    layer16w(hbuf, pw1, b1, 16, wave, lane);   // 512 -> 512, relu
    layer16w(hbuf, pw2, b2, 16, wave, lane);   // 512 -> 512, relu

    // layer 3: 512 -> 128. 32 cells = 16 waves x (1 ntile x 2 mtiles).
    // Wave w: ntile w&7, mtiles {(w>>3)*2, (w>>3)*2+1}. pw3 kt-stride 4096.
    {
        const int nt8 = wave & 7;
        const int mb  = (wave >> 3) * 2;
        const unsigned base0 = (unsigned)(mb * 16384 + l15 * 1024 + (lhi << 4));
        const unsigned xmask = ((unsigned)l15) << 4;
        f32x4 acc[2];
        acc[0] = (f32x4){0.f, 0.f, 0.f, 0.f};
        acc[1] = (f32x4){0.f, 0.f, 0.f, 0.f};

        const short* p = pw3 + (nt8 << 9) + (lane << 3);
        for (int kt = 0; kt < 16; ++kt) {
            bf16x8 b = *(const bf16x8*)(p);
            const char* ab = hbuf + ((base0 + (unsigned)kt * 64u) ^ xmask);
            bf16x8 a0 = *(const bf16x8*)(ab);
            bf16x8 a1 = *(const bf16x8*)(ab + 16384);
            acc[0] = __builtin_amdgcn_mfma_f32_16x16x32_bf16(a0, b, acc[0], 0, 0, 0);
            acc[1] = __builtin_amdgcn_mfma_f32_16x16x32_bf16(a1, b, acc[1], 0, 0, 0);
            p += 4096;
        }
        __syncthreads();   // done reading bf16 h; reuse hbuf as [64][128] fp32

        int colg = nt8 * 16 + l15;
        float bv = b3[colg];
        #pragma unroll
        for (int mt = 0; mt < 2; ++mt) {
            #pragma unroll
            for (int r = 0; r < 4; ++r) {
                int row = (mb + mt) * 16 + (lhi << 2) + r;
                *(float*)(hbuf + swzf((unsigned)(row * 512 + colg * 4))) = acc[mt][r] + bv;
            }
        }
        __syncthreads();

        #pragma unroll
        for (int pass = 0; pass < 2; ++pass) {
            unsigned int L = (unsigned)(pass * 1024 + tid) * 16;
            f32x4v v = *(const f32x4v*)(hbuf + swzf(L));
            if (is_tgt) __builtin_nontemporal_store(v, (f32x4v*)(zout + (L >> 2)));
            else        *(f32x4v*)(zout + (L >> 2)) = v;
        }
    }
}

// ---------------------------------------------------------------------------
// 2-step unrolled recurrence + fused decoder — R13-VERBATIM.
// ---------------------------------------------------------------------------
#define RR4 4
__global__ __launch_bounds__(512, 4) void recurrence2_kernel(
    const float* __restrict__ zk, const float* __restrict__ u,
    const float* __restrict__ Bw, const float* __restrict__ Aw,
    const float* __restrict__ A2, const float* __restrict__ Cw,
    const float* __restrict__ Cb,
    float* __restrict__ zpred, float* __restrict__ xpred) {
    __shared__ float z_lds[RR4][128];
    __shared__ float part[4][8][128];
    __shared__ float zoutb[2][RR4][128];
    __shared__ float u_lds[RR4 * M_SEQ * CDIM];
    __shared__ float Bw_lds[CDIM * 128];
    __shared__ float Ct_lds[32 * 132];
    __shared__ float cb_lds[SDIM];
    const int tid   = threadIdx.x;
    const int col   = tid & 127;
    const int slice = tid >> 7;
    const int b0    = blockIdx.x * RR4;

    float a1[32], a2r[32], ba[16];
    #pragma unroll
    for (int i = 0; i < 32; ++i) {
        a1[i]  = Aw[(size_t)(slice * 32 + i) * 128 + col];
        a2r[i] = A2[(size_t)(slice * 32 + i) * 128 + col];
    }

    if (tid < RR4 * 128)
        z_lds[tid >> 7][tid & 127] = zk[(size_t)(b0 + (tid >> 7)) * 128 + (tid & 127)];
    for (int id = tid; id < CDIM * 128; id += 512) Bw_lds[id] = Bw[id];
    for (int id = tid; id < RR4 * M_SEQ * CDIM; id += 512)
        u_lds[id] = u[(size_t)b0 * M_SEQ * CDIM + id];
    for (int id = tid; id < 128 * 32; id += 512) {
        int k = id >> 5, c = id & 31;
        Ct_lds[c * 132 + k] = Cw[id];
    }
    if (tid < SDIM) cb_lds[tid] = Cb[tid];
    __syncthreads();

    #pragma unroll
    for (int c = 0; c < 8; ++c) {
        float s = 0.f;
        #pragma unroll
        for (int kk = 0; kk < 32; ++kk) s += Bw_lds[c * 128 + slice * 32 + kk] * a1[kk];
        part[slice][c][col] = s;
    }
    __syncthreads();
    #pragma unroll
    for (int c = 0; c < 8; ++c) {
        ba[c]     = Bw_lds[c * 128 + col];
        ba[8 + c] = part[0][c][col] + part[1][c][col] + part[2][c][col] + part[3][c][col];
    }
    __syncthreads();

    for (int r = 0; r < 32; ++r) {
        const int m0 = 2 * r;
        #pragma unroll
        for (int b = 0; b < RR4; ++b) {
            const float4* z4 = (const float4*)&z_lds[b][slice * 32];
            float p1 = 0.f, p2 = 0.f;
            #pragma unroll
            for (int i = 0; i < 8; ++i) {
                float4 zv = z4[i];
                p1 += a1[i*4+0]*zv.x + a1[i*4+1]*zv.y + a1[i*4+2]*zv.z + a1[i*4+3]*zv.w;
                p2 += a2r[i*4+0]*zv.x + a2r[i*4+1]*zv.y + a2r[i*4+2]*zv.z + a2r[i*4+3]*zv.w;
            }
            part[slice][b * 2 + 0][col] = p1;
            part[slice][b * 2 + 1][col] = p2;
        }
        if (r > 0 && tid < 256) {
            const int mprev = 2 * (r - 1);
            int sb = tid >> 5, c32 = tid & 31;
            int s = sb >> 2, b = sb & 3;
            float acc = cb_lds[c32];
            const float4* z4 = (const float4*)&zoutb[s][b][0];
            const float4* c4 = (const float4*)&Ct_lds[c32 * 132];
            #pragma unroll
            for (int i = 0; i < 32; ++i) {
                float4 zv = z4[i], cv = c4[i];
                acc += zv.x*cv.x + zv.y*cv.y + zv.z*cv.z + zv.w*cv.w;
            }
            __builtin_nontemporal_store(acc,
                xpred + ((size_t)(b0 + b) * M_SEQ + (mprev + s)) * SDIM + c32);
        }
        __syncthreads();
        {
            const int b = slice;
            float v0 = part[0][b*2+0][col] + part[1][b*2+0][col] + part[2][b*2+0][col] + part[3][b*2+0][col];
            float v1 = part[0][b*2+1][col] + part[1][b*2+1][col] + part[2][b*2+1][col] + part[3][b*2+1][col];
            const float4* uu0 = (const float4*)&u_lds[(b * M_SEQ + m0) * CDIM];
            float4 ua = uu0[0], ub = uu0[1];
            v0 += ua.x*ba[0] + ua.y*ba[1] + ua.z*ba[2] + ua.w*ba[3]
                + ub.x*ba[4] + ub.y*ba[5] + ub.z*ba[6] + ub.w*ba[7];
            v1 += ua.x*ba[8] + ua.y*ba[9] + ua.z*ba[10] + ua.w*ba[11]
                + ub.x*ba[12] + ub.y*ba[13] + ub.z*ba[14] + ub.w*ba[15];
            const float4* uu1 = (const float4*)&u_lds[(b * M_SEQ + m0 + 1) * CDIM];
            float4 uc = uu1[0], ud = uu1[1];
            v1 += uc.x*ba[0] + uc.y*ba[1] + uc.z*ba[2] + uc.w*ba[3]
                + ud.x*ba[4] + ud.y*ba[5] + ud.z*ba[6] + ud.w*ba[7];
            zoutb[0][b][col] = v0;
            zoutb[1][b][col] = v1;
            z_lds[b][col] = v1;
            __builtin_nontemporal_store(v0, zpred + ((size_t)(b0 + b) * M_SEQ + m0) * 128 + col);
            __builtin_nontemporal_store(v1, zpred + ((size_t)(b0 + b) * M_SEQ + m0 + 1) * 128 + col);
        }
        __syncthreads();
    }
    if (tid < 256) {
        const int mprev = 62;
        int sb = tid >> 5, c32 = tid & 31;
        int s = sb >> 2, b = sb & 3;
        float acc = cb_lds[c32];
        const float4* z4 = (const float4*)&zoutb[s][b][0];
        const float4* c4 = (const float4*)&Ct_lds[c32 * 132];
        #pragma unroll
        for (int i = 0; i < 32; ++i) {
            float4 zv = z4[i], cv = c4[i];
            acc += zv.x*cv.x + zv.y*cv.y + zv.z*cv.z + zv.w*cv.w;
        }
        __builtin_nontemporal_store(acc,
            xpred + ((size_t)(b0 + b) * M_SEQ + (mprev + s)) * SDIM + c32);
    }
}

extern "C" void kernel_launch(void* const* d_in, const int* in_sizes, int n_in,
                              void* d_out, int out_size, void* d_ws, size_t ws_size,
                              hipStream_t stream) {
    const float* x_k    = (const float*)d_in[0];
    const float* u_seq  = (const float*)d_in[1];
    const float* x_next = (const float*)d_in[2];
    const float* w0 = (const float*)d_in[3];  const float* b0 = (const float*)d_in[4];
    const float* w1 = (const float*)d_in[5];  const float* b1 = (const float*)d_in[6];
    const float* w2 = (const float*)d_in[7];  const float* b2 = (const float*)d_in[8];
    const float* w3 = (const float*)d_in[9];  const float* b3 = (const float*)d_in[10];
    const float* A_w = (const float*)d_in[11];
    const float* B_w = (const float*)d_in[12];
    const float* C_w = (const float*)d_in[13];
    const float* C_b = (const float*)d_in[14];

    float* out    = (float*)d_out;
    float* z_pred = out;                                   // 2048*64*128
    float* x_pred = out + (size_t)NROWS_NEXT * LDIM;       // 2048*64*32
    float* z_tgt  = x_pred + (size_t)NROWS_NEXT * SDIM;    // 2048*64*128

    char* ws = (char*)d_ws;
    short* pw0 = (short*)(ws);                                     // 32 KB
    short* pw1 = (short*)(ws + 32768);                             // 512 KB
    short* pw2 = (short*)(ws + 32768 + 524288);                    // 512 KB
    short* pw3 = (short*)(ws + 32768 + 2 * 524288);                // 128 KB
    float* z_k_buf = (float*)(ws + 32768 + 2 * 524288 + 131072);   // 1 MB
    float* A2_buf  = (float*)(ws + 32768 + 2 * 524288 + 131072 + 1048576);  // 64 KB

    mm128<<<128, 128, 0, stream>>>(A_w, A_w, A2_buf);

    pack_all<<<(P_S3 + 255) / 256, 256, 0, stream>>>(w0, w1, w2, w3, pw0, pw1, pw2, pw3);

    encoder_kernel<<<NROWS_ALL / 64, 1024, 0, stream>>>(
        x_next, x_k, pw0, pw1, pw2, pw3, b0, b1, b2, b3, z_tgt, z_k_buf);

    recurrence2_kernel<<<B_TOT / RR4, 512, 0, stream>>>(
        z_k_buf, u_seq, B_w, A_w, A2_buf, C_w, C_b, z_pred, x_pred);
}